// Round 4
// baseline (490.247 us; speedup 1.0000x reference)
//
#include <hip/hip_runtime.h>
#include <cmath>

#define TPB 256

static const int NTOK  = 1025;
static const int DIM   = 768;
static const int HEADS = 12;
static const int DH    = 64;
static const int QK3   = 2304;
static const int ROWS  = 4 * NTOK;        // 4100
static const int MROWS = 4 * (NTOK - 1);  // 4096
static const int MPAD  = 4224;            // 33*128 padded A rows
static const int NPAD  = 1088;            // 17*64
static const int VROWS = 129;             // 128 V cols + 1 ones-row (l_i column)
static const size_t OUT0 = (size_t)ROWS * DIM;
static const size_t APLANE = (size_t)MPAD * DIM;   // bf16 per plane

// workspace offsets in floats
static const size_t OFF_QKV  = 0;          // 9,446,400 f
static const size_t OFF_QKVM = 9446400;    // 9,437,184 f
static const size_t OFF_QE   = 18883584;   // 1,671,168 f (bf16)
static const size_t OFF_KE   = 20554752;   // 1,671,168 f
static const size_t OFF_VT   = 22225920;   // 48*129*1088 bf16 = 3,368,448 f
static const size_t OFF_ABF  = 25594368;   // bf16 [2][4224][768] = 3,244,032 f
static const size_t OFF_WQ   = 28838400;   // bf16 [2][2304][768] = 1,769,472 f
static const size_t OFF_WO   = 30607872;   // bf16 [2][768][768]  =   589,824 f
static const size_t OFF_CMAX = 31197696;   // 9,216 f
static const size_t OFF_UPD  = 31206912;   // 4,100 f
// note: k_attn's ones-group b128 loads over-read ~33 KB past VT's end into ABF
// (valid mapped ws, finite bf16 garbage) — those lanes' acc components are never used.

typedef __attribute__((ext_vector_type(8))) short short8;
typedef __attribute__((ext_vector_type(4))) float f32x4;

__device__ __forceinline__ unsigned short f2bf(float f) {
    union { float f; unsigned int u; } c; c.f = f;
    unsigned int u = c.u + 0x7fffu + ((c.u >> 16) & 1u);  // RNE
    return (unsigned short)(u >> 16);
}

__device__ __forceinline__ void gl_lds16(const unsigned short* g, unsigned short* l) {
    __builtin_amdgcn_global_load_lds(
        (const __attribute__((address_space(1))) unsigned int*)g,
        (__attribute__((address_space(3))) unsigned int*)l, 16, 0, 0);
}

// ---------------------------------------------------------------------------
// K0: fp32 -> bf16 conversions (unchanged)
// ---------------------------------------------------------------------------
__global__ __launch_bounds__(TPB)
void k_cvt(const float* __restrict__ x, const float* __restrict__ mask,
           const float* __restrict__ wqkv, const float* __restrict__ wout,
           unsigned short* __restrict__ Abf, unsigned short* __restrict__ Wq,
           unsigned short* __restrict__ Wo)
{
    const int z = blockIdx.z;
    const size_t idx = ((size_t)blockIdx.x * TPB + threadIdx.x) * 8;
    unsigned short o[8] __attribute__((aligned(16)));
    if (z <= 1) {
        if (idx >= APLANE) return;
        const int row = (int)(idx / DIM);
        const int M = z ? MROWS : ROWS;
        const float* src = z ? mask : x;
        if (row < M) {
            float a[8];
            *(float4*)&a[0] = *(const float4*)(src + idx);
            *(float4*)&a[4] = *(const float4*)(src + idx + 4);
#pragma unroll
            for (int i = 0; i < 8; ++i) o[i] = f2bf(a[i]);
        } else {
#pragma unroll
            for (int i = 0; i < 8; ++i) o[i] = 0;
        }
        *(short8*)(Abf + (size_t)z * APLANE + idx) = *(short8*)o;
    } else {
        const size_t tot = (z == 2) ? (size_t)QK3 * DIM : (size_t)DIM * DIM;
        if (idx >= tot) return;
        const float* src = (z == 2) ? wqkv : wout;
        unsigned short* dst = (z == 2) ? Wq : Wo;
        float a[8];
        *(float4*)&a[0] = *(const float4*)(src + idx);
        *(float4*)&a[4] = *(const float4*)(src + idx + 4);
        unsigned short oa[8] __attribute__((aligned(16)));
#pragma unroll
        for (int i = 0; i < 8; ++i) { o[i] = f2bf(a[i]); oa[i] = f2bf(fabsf(a[i])); }
        *(short8*)(dst + idx) = *(short8*)o;
        *(short8*)(dst + tot + idx) = *(short8*)oa;
    }
}

// ---------------------------------------------------------------------------
// K1: bf16 MFMA GEMM (m97 recipe) — unchanged
// ---------------------------------------------------------------------------
__global__ __launch_bounds__(TPB)
void k_gemm_qkv_mfma(const unsigned short* __restrict__ Abf,
                     const unsigned short* __restrict__ Wq,
                     float* __restrict__ qkv, float* __restrict__ qkvm)
{
    const int z = blockIdx.z;
    const unsigned short* A = Abf + (size_t)z * APLANE;
    const unsigned short* B = Wq + (size_t)z * QK3 * DIM;
    float* C = z ? qkvm : qkv;
    const int M = z ? MROWS : ROWS;

    __shared__ unsigned short As[128 * 32];
    __shared__ unsigned short Bs[128 * 32];

    const int t = threadIdx.x;
    const int w = t >> 6, lane = t & 63, l15 = lane & 15, quad = lane >> 4;
    const int rowT = blockIdx.y * 128, colT = blockIdx.x * 128;
    const int wm = (w & 1) * 64, wn = (w >> 1) * 64;

    const int r0 = t >> 2, kc = (t & 3) * 8;
    const unsigned short* Ap = A + (size_t)(rowT + r0) * DIM + kc;
    const unsigned short* Bp = B + (size_t)(colT + r0) * DIM + kc;

    f32x4 acc[4][4];
#pragma unroll
    for (int i = 0; i < 4; ++i)
#pragma unroll
        for (int j = 0; j < 4; ++j) acc[i][j] = (f32x4){0.f, 0.f, 0.f, 0.f};

    for (int k0 = 0; k0 < DIM; k0 += 32) {
        __syncthreads();
        gl_lds16(Ap + k0,            As + t * 8);
        gl_lds16(Ap + 64 * DIM + k0, As + (t + 256) * 8);
        gl_lds16(Bp + k0,            Bs + t * 8);
        gl_lds16(Bp + 64 * DIM + k0, Bs + (t + 256) * 8);
        __syncthreads();
        short8 fa[4], fb[4];
#pragma unroll
        for (int mi = 0; mi < 4; ++mi)
            fa[mi] = *(const short8*)(As + (wm + mi * 16 + l15) * 32 + quad * 8);
#pragma unroll
        for (int ni = 0; ni < 4; ++ni)
            fb[ni] = *(const short8*)(Bs + (wn + ni * 16 + l15) * 32 + quad * 8);
#pragma unroll
        for (int mi = 0; mi < 4; ++mi)
#pragma unroll
            for (int ni = 0; ni < 4; ++ni)
                acc[mi][ni] = __builtin_amdgcn_mfma_f32_16x16x32_bf16(fa[mi], fb[ni], acc[mi][ni], 0, 0, 0);
    }
#pragma unroll
    for (int mi = 0; mi < 4; ++mi)
#pragma unroll
        for (int ni = 0; ni < 4; ++ni) {
            const int col = colT + wn + ni * 16 + l15;
#pragma unroll
            for (int r = 0; r < 4; ++r) {
                const int row = rowT + wm + mi * 16 + quad * 4 + r;
                if (row < M) C[(size_t)row * QK3 + col] = acc[mi][ni][r];
            }
        }
}

// ---------------------------------------------------------------------------
// K2a: column max of qkv_m (unchanged)
// ---------------------------------------------------------------------------
__global__ __launch_bounds__(TPB)
void k_colmax(const float* __restrict__ qkvm, float* __restrict__ cmax)
{
    __shared__ float red[4][64];
    const int t = threadIdx.x;
    const int cl = t & 63, rg = t >> 6;
    const int col = blockIdx.x * 64 + cl;
    const int b = blockIdx.y;
    const float* p = qkvm + (size_t)b * 1024 * QK3 + col;
    float mx = 0.f;
    const int n0 = rg * 256;
    for (int n = 0; n < 256; ++n) mx = fmaxf(mx, p[(size_t)(n0 + n) * QK3]);
    red[rg][cl] = mx;
    __syncthreads();
    if (rg == 0) {
        mx = fmaxf(fmaxf(red[0][cl], red[1][cl]), fmaxf(red[2][cl], red[3][cl]));
        cmax[b * QK3 + col] = mx;
    }
}

// ---------------------------------------------------------------------------
// K2b: updated[b,n] (unchanged)
// ---------------------------------------------------------------------------
__global__ __launch_bounds__(TPB)
void k_upd(const float* __restrict__ mask, float* __restrict__ upd)
{
    const int w = threadIdx.x >> 6, lane = threadIdx.x & 63;
    const int r = blockIdx.x * 4 + w;
    if (r >= ROWS) return;
    const int b = r / NTOK, n = r % NTOK;
    float res = 1.f;
    if (n > 0) {
        const float* p = mask + (size_t)(b * (NTOK - 1) + (n - 1)) * DIM;
        float s = 0.f;
        for (int i = lane; i < DIM; i += 64) s += p[i];
#pragma unroll
        for (int off = 32; off > 0; off >>= 1) s += __shfl_xor(s, off, 64);
        res = (s > 0.f) ? 1.f : 0.f;
    }
    if (lane == 0) upd[r] = res;
}

// ---------------------------------------------------------------------------
// K2c: vt ones-row (row 128 per bh): 1.0 for n<NTOK else 0 — the l_i column
// ---------------------------------------------------------------------------
__global__ __launch_bounds__(TPB)
void k_ones(unsigned short* __restrict__ vt)
{
    const int bh = blockIdx.x;
    unsigned short* p = vt + ((size_t)bh * VROWS + 128) * NPAD;
    for (int n = threadIdx.x; n < NPAD; n += TPB)
        p[n] = (n < NTOK) ? (unsigned short)0x3F80 : (unsigned short)0;
}

// ---------------------------------------------------------------------------
// K3: qe/ke bf16 [bh,1088,64], vt bf16 transposed [bh,129(VROWS),1088]
// ---------------------------------------------------------------------------
__global__ __launch_bounds__(TPB)
void k_prep(const float* __restrict__ qkv, const float* __restrict__ qkvm,
            const float* __restrict__ cmax, unsigned short* __restrict__ qe,
            unsigned short* __restrict__ ke, unsigned short* __restrict__ vt)
{
    __shared__ unsigned short Vt_l[128 * 66];
    const int t = threadIdx.x;
    const int nt = blockIdx.x, h = blockIdx.y, b = blockIdx.z;
    const int bh = b * HEADS + h;
    const int nl = t >> 2, ds0 = (t & 3) * 16;
    const int n = nt * 64 + nl;
    const bool valid = n < NTOK;
    const int col0 = h * DH + ds0;

    unsigned short oq[16] __attribute__((aligned(16)));
    unsigned short ok[16] __attribute__((aligned(16)));

    const size_t row  = (size_t)(b * NTOK + n) * QK3 + col0;
    const size_t mrow = (size_t)(b * 1024 + (n - 1)) * QK3 + col0;
    const int cb = b * QK3 + col0;

#pragma unroll
    for (int i = 0; i < 4; ++i) {
        float qa[4] = {0, 0, 0, 0}, ka[4] = {0, 0, 0, 0}, va[4] = {0, 0, 0, 0};
        float qma[4] = {1, 1, 1, 1}, kma[4] = {1, 1, 1, 1}, vma[4] = {1, 1, 1, 1};
        if (valid) {
            *(float4*)qa = *(const float4*)(qkv + row + i * 4);
            *(float4*)ka = *(const float4*)(qkv + row + 768 + i * 4);
            *(float4*)va = *(const float4*)(qkv + row + 1536 + i * 4);
            if (n > 0) {
                *(float4*)qma = *(const float4*)(qkvm + mrow + i * 4);
                *(float4*)kma = *(const float4*)(qkvm + mrow + 768 + i * 4);
                *(float4*)vma = *(const float4*)(qkvm + mrow + 1536 + i * 4);
#pragma unroll
                for (int j = 0; j < 4; ++j) {
                    qma[j] /= (1e-6f + cmax[cb + i * 4 + j]);
                    kma[j] /= (1e-6f + cmax[cb + 768 + i * 4 + j]);
                    vma[j] /= (1e-6f + cmax[cb + 1536 + i * 4 + j]);
                }
            }
        }
#pragma unroll
        for (int j = 0; j < 4; ++j) {
            const int idx = i * 4 + j, d = ds0 + idx;
            oq[idx] = f2bf(qa[j] * qma[j] * 0.125f);
            ok[idx] = f2bf(ka[j] * kma[j]);
            const float vmv = valid ? vma[j] : 0.f;
            Vt_l[d * 66 + nl]        = f2bf(va[j] * vmv);
            Vt_l[(64 + d) * 66 + nl] = f2bf(vmv);
        }
    }
    if (valid) {
        unsigned short* qp = qe + ((size_t)bh * NPAD + n) * 64 + ds0;
        unsigned short* kp = ke + ((size_t)bh * NPAD + n) * 64 + ds0;
        *(short8*)qp       = *(short8*)oq;
        *(short8*)(qp + 8) = *(short8*)(oq + 8);
        *(short8*)kp       = *(short8*)ok;
        *(short8*)(kp + 8) = *(short8*)(ok + 8);
    }
    __syncthreads();
    const int c = t >> 1, nh = (t & 1) * 32;
    unsigned short ov[32] __attribute__((aligned(16)));
#pragma unroll
    for (int i = 0; i < 32; ++i) ov[i] = Vt_l[c * 66 + nh + i];
    unsigned short* vp = vt + ((size_t)bh * VROWS + c) * NPAD + nt * 64 + nh;
#pragma unroll
    for (int i = 0; i < 4; ++i) *(short8*)(vp + i * 8) = *(short8*)(ov + i * 8);
}

// ---------------------------------------------------------------------------
// K4: barrier-free MFMA flash attention.
// Each wave independently owns a 16-row q-tile; K/V fragments loaded directly
// global->VGPR (b128, L2-resident); only the P C->A transform uses LDS
// (wave-private 2KB slice). l_i accumulated by MFMA via V's ones-column
// (group 8); running rescale by alpha covers it automatically.
// ---------------------------------------------------------------------------
__global__ __launch_bounds__(TPB, 3)
void k_attn(const unsigned short* __restrict__ qe, const unsigned short* __restrict__ ke,
            const unsigned short* __restrict__ vt, const float* __restrict__ upd,
            unsigned short* __restrict__ ab2)
{
    __shared__ short8 PsF[8 * 64];   // 2 groups per wave (wave-private slices)

    const int t = threadIdx.x;
    const int w = t >> 6, lane = t & 63;
    const int l15 = lane & 15, quad = lane >> 4;
    const int bh = blockIdx.y;
    const int b = bh / HEADS, h = bh % HEADS;
    const int qt = blockIdx.x * 4 + w;     // 16-row q tile, 0..67
    if (qt >= 65) return;                  // no barriers in this kernel
    const int q0 = qt * 16;

    // Q A-fragments (whole wave-tile, held in regs)
    short8 qf0, qf1;
    {
        const unsigned short* qp = qe + ((size_t)bh * NPAD + q0 + l15) * 64 + (quad << 3);
        qf0 = *(const short8*)qp;
        qf1 = *(const short8*)(qp + 32);
    }
    // fragment base pointers (lane-fixed parts folded in)
    const unsigned short* kbase = ke + ((size_t)bh * NPAD + l15) * 64 + (quad << 3);
    const unsigned short* vbase = vt + ((size_t)bh * VROWS + l15) * NPAD + (quad << 3);

    float m_i[4];
    f32x4 acc[9];                      // 0..7 = 128 out cols, 8 = l_i column
#pragma unroll
    for (int r = 0; r < 4; ++r) m_i[r] = -INFINITY;
#pragma unroll
    for (int g = 0; g < 9; ++g) acc[g] = (f32x4){0.f, 0.f, 0.f, 0.f};

    unsigned short* Pw = (unsigned short*)&PsF[w * 2 * 64];

    for (int kt = 0; kt < 17; ++kt) {
        const int kn0 = kt * 64;
        const unsigned short* kcol = kbase + (size_t)kn0 * 64;

        // V kk=0 fragments (9 groups incl ones-column) — issue early
        short8 vf0[9];
#pragma unroll
        for (int g = 0; g < 9; ++g)
            vf0[g] = *(const short8*)(vbase + (size_t)(g * 16) * NPAD + kn0);

        // S = Q K^T (K fragments direct from global)
        f32x4 s[4];
#pragma unroll
        for (int nc = 0; nc < 4; ++nc) {
            const short8 k0 = *(const short8*)(kcol + nc * 1024);
            const short8 k1 = *(const short8*)(kcol + nc * 1024 + 32);
            f32x4 z = (f32x4){0.f, 0.f, 0.f, 0.f};
            z = __builtin_amdgcn_mfma_f32_16x16x32_bf16(qf0, k0, z, 0, 0, 0);
            z = __builtin_amdgcn_mfma_f32_16x16x32_bf16(qf1, k1, z, 0, 0, 0);
            s[nc] = z;
        }
        if (kt == 16) {   // only the last tile has invalid kv cols (>=1025)
#pragma unroll
            for (int nc = 0; nc < 4; ++nc)
                if (nc * 16 + l15 >= 1) {
                    s[nc][0] = -INFINITY; s[nc][1] = -INFINITY;
                    s[nc][2] = -INFINITY; s[nc][3] = -INFINITY;
                }
        }
        // online softmax (max only; sum comes from the MFMA ones-column)
        float mx[4], alpha[4];
#pragma unroll
        for (int r = 0; r < 4; ++r)
            mx[r] = fmaxf(fmaxf(s[0][r], s[1][r]), fmaxf(s[2][r], s[3][r]));
#pragma unroll
        for (int r = 0; r < 4; ++r) {
            mx[r] = fmaxf(mx[r], __shfl_xor(mx[r], 1, 64));
            mx[r] = fmaxf(mx[r], __shfl_xor(mx[r], 2, 64));
            mx[r] = fmaxf(mx[r], __shfl_xor(mx[r], 4, 64));
            mx[r] = fmaxf(mx[r], __shfl_xor(mx[r], 8, 64));
            const float mnew = fmaxf(m_i[r], mx[r]);
            alpha[r] = __expf(m_i[r] - mnew);
            m_i[r] = mnew;
        }
#pragma unroll
        for (int nc = 0; nc < 4; ++nc)
#pragma unroll
            for (int r = 0; r < 4; ++r)
                s[nc][r] = __expf(s[nc][r] - m_i[r]);
#pragma unroll
        for (int g = 0; g < 9; ++g) {
            acc[g][0] *= alpha[0]; acc[g][1] *= alpha[1];
            acc[g][2] *= alpha[2]; acc[g][3] *= alpha[3];
        }
        // P: C-layout regs -> A-layout LDS (wave-private)
#pragma unroll
        for (int nc = 0; nc < 4; ++nc) {
            const int k = nc * 16 + l15;
            const int kk = nc >> 1;
            const int sb = ((k >> 3) & 3) << 4;
            const int j = k & 7;
#pragma unroll
            for (int r = 0; r < 4; ++r)
                Pw[kk * 512 + (quad * 4 + r + sb) * 8 + j] = f2bf(s[nc][r]);
        }
        // V kk=1 fragments — issue while P settles
        short8 vf1[9];
#pragma unroll
        for (int g = 0; g < 9; ++g)
            vf1[g] = *(const short8*)(vbase + (size_t)(g * 16) * NPAD + kn0 + 32);

        const short8 pf0 = PsF[(w * 2 + 0) * 64 + lane];
        const short8 pf1 = PsF[(w * 2 + 1) * 64 + lane];
#pragma unroll
        for (int g = 0; g < 9; ++g) {
            acc[g] = __builtin_amdgcn_mfma_f32_16x16x32_bf16(pf0, vf0[g], acc[g], 0, 0, 0);
            acc[g] = __builtin_amdgcn_mfma_f32_16x16x32_bf16(pf1, vf1[g], acc[g], 0, 0, 0);
        }
    }

    // broadcast l_i (lives in l15==0 lanes of each quad, acc[8])
    float lb[4];
#pragma unroll
    for (int r = 0; r < 4; ++r) lb[r] = __shfl(acc[8][r], lane & 48, 64);

#pragma unroll
    for (int r = 0; r < 4; ++r) {
        const int row = q0 + quad * 4 + r;
        if (row < NTOK) {
            const size_t rg = (size_t)b * NTOK + row;
            const float inv = upd[rg] / lb[r];
#pragma unroll
            for (int g = 0; g < 8; ++g) {
                const int c = g * 16 + l15;
                const size_t addr = (size_t)(c >> 6) * APLANE + rg * DIM + h * 64 + (c & 63);
                ab2[addr] = f2bf(acc[g][r] * inv);
            }
        }
    }
}

// ---------------------------------------------------------------------------
// K5: bf16 MFMA out-GEMMs (unchanged)
// ---------------------------------------------------------------------------
__global__ __launch_bounds__(TPB)
void k_gemm_out_mfma(const unsigned short* __restrict__ ab2,
                     const unsigned short* __restrict__ Wo,
                     const float* __restrict__ bout, float* __restrict__ dout)
{
    const int z = blockIdx.z;
    const unsigned short* A = ab2 + (size_t)z * APLANE;
    const unsigned short* B = Wo + (size_t)z * DIM * DIM;

    __shared__ unsigned short As[128 * 32];
    __shared__ unsigned short Bs[128 * 32];

    const int t = threadIdx.x;
    const int w = t >> 6, lane = t & 63, l15 = lane & 15, quad = lane >> 4;
    const int rowT = blockIdx.y * 128, colT = blockIdx.x * 128;
    const int wm = (w & 1) * 64, wn = (w >> 1) * 64;

    const int r0 = t >> 2, kc = (t & 3) * 8;
    const unsigned short* Ap = A + (size_t)(rowT + r0) * DIM + kc;
    const unsigned short* Bp = B + (size_t)(colT + r0) * DIM + kc;

    f32x4 acc[4][4];
#pragma unroll
    for (int i = 0; i < 4; ++i)
#pragma unroll
        for (int j = 0; j < 4; ++j) acc[i][j] = (f32x4){0.f, 0.f, 0.f, 0.f};

    for (int k0 = 0; k0 < DIM; k0 += 32) {
        __syncthreads();
        gl_lds16(Ap + k0,            As + t * 8);
        gl_lds16(Ap + 64 * DIM + k0, As + (t + 256) * 8);
        gl_lds16(Bp + k0,            Bs + t * 8);
        gl_lds16(Bp + 64 * DIM + k0, Bs + (t + 256) * 8);
        __syncthreads();
        short8 fa[4], fb[4];
#pragma unroll
        for (int mi = 0; mi < 4; ++mi)
            fa[mi] = *(const short8*)(As + (wm + mi * 16 + l15) * 32 + quad * 8);
#pragma unroll
        for (int ni = 0; ni < 4; ++ni)
            fb[ni] = *(const short8*)(Bs + (wn + ni * 16 + l15) * 32 + quad * 8);
#pragma unroll
        for (int mi = 0; mi < 4; ++mi)
#pragma unroll
            for (int ni = 0; ni < 4; ++ni)
                acc[mi][ni] = __builtin_amdgcn_mfma_f32_16x16x32_bf16(fa[mi], fb[ni], acc[mi][ni], 0, 0, 0);
    }
#pragma unroll
    for (int mi = 0; mi < 4; ++mi)
#pragma unroll
        for (int ni = 0; ni < 4; ++ni) {
            const int col = colT + wn + ni * 16 + l15;
            const float bb = (z == 0) ? bout[col] : 0.f;
#pragma unroll
            for (int r = 0; r < 4; ++r) {
                const int row = rowT + wm + mi * 16 + quad * 4 + r;
                if (row >= ROWS) continue;
                const int b = row / NTOK, n = row % NTOK;
                if (z == 0) {
                    dout[(size_t)row * DIM + col] = acc[mi][ni][r] + bb;
                } else if (n >= 1) {
                    dout[OUT0 + ((size_t)(b * (NTOK - 1) + (n - 1))) * DIM + col] = acc[mi][ni][r];
                }
            }
        }
}

extern "C" void kernel_launch(void* const* d_in, const int* in_sizes, int n_in,
                              void* d_out, int out_size, void* d_ws, size_t ws_size,
                              hipStream_t stream)
{
    const float* x    = (const float*)d_in[0];
    const float* mask = (const float*)d_in[1];
    const float* wqkv = (const float*)d_in[2];
    const float* wout = (const float*)d_in[3];
    const float* bout = (const float*)d_in[4];
    float* ws   = (float*)d_ws;
    float* qkv  = ws + OFF_QKV;
    float* qkvm = ws + OFF_QKVM;
    unsigned short* qe  = (unsigned short*)(ws + OFF_QE);
    unsigned short* ke  = (unsigned short*)(ws + OFF_KE);
    unsigned short* vt  = (unsigned short*)(ws + OFF_VT);
    unsigned short* abf = (unsigned short*)(ws + OFF_ABF);
    unsigned short* wq  = (unsigned short*)(ws + OFF_WQ);
    unsigned short* wo  = (unsigned short*)(ws + OFF_WO);
    float* cmax = ws + OFF_CMAX;
    float* upd  = ws + OFF_UPD;
    float* out  = (float*)d_out;

    hipLaunchKernelGGL(k_cvt,           dim3(1584, 1, 4), dim3(TPB), 0, stream, x, mask, wqkv, wout, abf, wq, wo);
    hipLaunchKernelGGL(k_gemm_qkv_mfma, dim3(18, 33, 2),  dim3(TPB), 0, stream, abf, wq, qkv, qkvm);
    hipLaunchKernelGGL(k_colmax,        dim3(36, 4),      dim3(TPB), 0, stream, qkvm, cmax);
    hipLaunchKernelGGL(k_upd,           dim3(1025),       dim3(TPB), 0, stream, mask, upd);
    hipLaunchKernelGGL(k_ones,          dim3(48),         dim3(TPB), 0, stream, vt);
    hipLaunchKernelGGL(k_prep,          dim3(17, 12, 4),  dim3(TPB), 0, stream, qkv, qkvm, cmax, qe, ke, vt);
    hipLaunchKernelGGL(k_attn,          dim3(17, 48),     dim3(TPB), 0, stream, qe, ke, vt, upd, abf);
    hipLaunchKernelGGL(k_gemm_out_mfma, dim3(6, 33, 2),   dim3(TPB), 0, stream, abf, wo, bout, out);
}

// Round 5
// 349.194 us; speedup vs baseline: 1.4039x; 1.4039x over previous
//
#include <hip/hip_runtime.h>
#include <cmath>

#define TPB 256

static const int NTOK  = 1025;
static const int DIM   = 768;
static const int HEADS = 12;
static const int DH    = 64;
static const int QK3   = 2304;
static const int ROWS  = 4 * NTOK;        // 4100
static const int MROWS = 4 * (NTOK - 1);  // 4096
static const int MPAD  = 4224;            // 33*128 padded A rows
static const int NPAD  = 1088;            // 17*64
static const int VROWS = 129;             // 128 V cols + 1 ones-row (l column)
static const size_t OUT0 = (size_t)ROWS * DIM;
static const size_t APLANE = (size_t)MPAD * DIM;   // bf16 per plane

// workspace offsets in floats
static const size_t OFF_QKV  = 0;          // 9,446,400 f
static const size_t OFF_QKVM = 9446400;    // 9,437,184 f
static const size_t OFF_QE   = 18883584;   // 1,671,168 f (bf16)
static const size_t OFF_KE   = 20554752;   // 1,671,168 f
static const size_t OFF_VT   = 22225920;   // 48*129*1088 bf16 = 3,368,448 f
static const size_t OFF_ABF  = 25594368;   // bf16 [2][4224][768] = 3,244,032 f
static const size_t OFF_WQ   = 28838400;   // bf16 [2][2304][768] = 1,769,472 f
static const size_t OFF_WO   = 30607872;   // bf16 [2][768][768]  =   589,824 f
static const size_t OFF_CMAX = 31197696;   // 9,216 f
static const size_t OFF_UPD  = 31206912;   // 4,100 f
// k_attn's ones-group V staging over-reads ~31 KB past VT's end into ABF
// (mapped ws, finite bf16) — those acc columns (l15>0 of acc[8]) are unused.

typedef __attribute__((ext_vector_type(8))) short short8;
typedef __attribute__((ext_vector_type(4))) float f32x4;

__device__ __forceinline__ unsigned short f2bf(float f) {
    union { float f; unsigned int u; } c; c.f = f;
    unsigned int u = c.u + 0x7fffu + ((c.u >> 16) & 1u);  // RNE
    return (unsigned short)(u >> 16);
}

__device__ __forceinline__ void gl_lds16(const unsigned short* g, unsigned short* l) {
    __builtin_amdgcn_global_load_lds(
        (const __attribute__((address_space(1))) unsigned int*)g,
        (__attribute__((address_space(3))) unsigned int*)l, 16, 0, 0);
}

// ---------------------------------------------------------------------------
// K0: fp32 -> bf16 conversions (unchanged)
// ---------------------------------------------------------------------------
__global__ __launch_bounds__(TPB)
void k_cvt(const float* __restrict__ x, const float* __restrict__ mask,
           const float* __restrict__ wqkv, const float* __restrict__ wout,
           unsigned short* __restrict__ Abf, unsigned short* __restrict__ Wq,
           unsigned short* __restrict__ Wo)
{
    const int z = blockIdx.z;
    const size_t idx = ((size_t)blockIdx.x * TPB + threadIdx.x) * 8;
    unsigned short o[8] __attribute__((aligned(16)));
    if (z <= 1) {
        if (idx >= APLANE) return;
        const int row = (int)(idx / DIM);
        const int M = z ? MROWS : ROWS;
        const float* src = z ? mask : x;
        if (row < M) {
            float a[8];
            *(float4*)&a[0] = *(const float4*)(src + idx);
            *(float4*)&a[4] = *(const float4*)(src + idx + 4);
#pragma unroll
            for (int i = 0; i < 8; ++i) o[i] = f2bf(a[i]);
        } else {
#pragma unroll
            for (int i = 0; i < 8; ++i) o[i] = 0;
        }
        *(short8*)(Abf + (size_t)z * APLANE + idx) = *(short8*)o;
    } else {
        const size_t tot = (z == 2) ? (size_t)QK3 * DIM : (size_t)DIM * DIM;
        if (idx >= tot) return;
        const float* src = (z == 2) ? wqkv : wout;
        unsigned short* dst = (z == 2) ? Wq : Wo;
        float a[8];
        *(float4*)&a[0] = *(const float4*)(src + idx);
        *(float4*)&a[4] = *(const float4*)(src + idx + 4);
        unsigned short oa[8] __attribute__((aligned(16)));
#pragma unroll
        for (int i = 0; i < 8; ++i) { o[i] = f2bf(a[i]); oa[i] = f2bf(fabsf(a[i])); }
        *(short8*)(dst + idx) = *(short8*)o;
        *(short8*)(dst + tot + idx) = *(short8*)oa;
    }
}

// ---------------------------------------------------------------------------
// K1: bf16 MFMA GEMM (m97 recipe) — unchanged
// ---------------------------------------------------------------------------
__global__ __launch_bounds__(TPB)
void k_gemm_qkv_mfma(const unsigned short* __restrict__ Abf,
                     const unsigned short* __restrict__ Wq,
                     float* __restrict__ qkv, float* __restrict__ qkvm)
{
    const int z = blockIdx.z;
    const unsigned short* A = Abf + (size_t)z * APLANE;
    const unsigned short* B = Wq + (size_t)z * QK3 * DIM;
    float* C = z ? qkvm : qkv;
    const int M = z ? MROWS : ROWS;

    __shared__ unsigned short As[128 * 32];
    __shared__ unsigned short Bs[128 * 32];

    const int t = threadIdx.x;
    const int w = t >> 6, lane = t & 63, l15 = lane & 15, quad = lane >> 4;
    const int rowT = blockIdx.y * 128, colT = blockIdx.x * 128;
    const int wm = (w & 1) * 64, wn = (w >> 1) * 64;

    const int r0 = t >> 2, kc = (t & 3) * 8;
    const unsigned short* Ap = A + (size_t)(rowT + r0) * DIM + kc;
    const unsigned short* Bp = B + (size_t)(colT + r0) * DIM + kc;

    f32x4 acc[4][4];
#pragma unroll
    for (int i = 0; i < 4; ++i)
#pragma unroll
        for (int j = 0; j < 4; ++j) acc[i][j] = (f32x4){0.f, 0.f, 0.f, 0.f};

    for (int k0 = 0; k0 < DIM; k0 += 32) {
        __syncthreads();
        gl_lds16(Ap + k0,            As + t * 8);
        gl_lds16(Ap + 64 * DIM + k0, As + (t + 256) * 8);
        gl_lds16(Bp + k0,            Bs + t * 8);
        gl_lds16(Bp + 64 * DIM + k0, Bs + (t + 256) * 8);
        __syncthreads();
        short8 fa[4], fb[4];
#pragma unroll
        for (int mi = 0; mi < 4; ++mi)
            fa[mi] = *(const short8*)(As + (wm + mi * 16 + l15) * 32 + quad * 8);
#pragma unroll
        for (int ni = 0; ni < 4; ++ni)
            fb[ni] = *(const short8*)(Bs + (wn + ni * 16 + l15) * 32 + quad * 8);
#pragma unroll
        for (int mi = 0; mi < 4; ++mi)
#pragma unroll
            for (int ni = 0; ni < 4; ++ni)
                acc[mi][ni] = __builtin_amdgcn_mfma_f32_16x16x32_bf16(fa[mi], fb[ni], acc[mi][ni], 0, 0, 0);
    }
#pragma unroll
    for (int mi = 0; mi < 4; ++mi)
#pragma unroll
        for (int ni = 0; ni < 4; ++ni) {
            const int col = colT + wn + ni * 16 + l15;
#pragma unroll
            for (int r = 0; r < 4; ++r) {
                const int row = rowT + wm + mi * 16 + quad * 4 + r;
                if (row < M) C[(size_t)row * QK3 + col] = acc[mi][ni][r];
            }
        }
}

// ---------------------------------------------------------------------------
// K2a: column max of qkv_m (unchanged)
// ---------------------------------------------------------------------------
__global__ __launch_bounds__(TPB)
void k_colmax(const float* __restrict__ qkvm, float* __restrict__ cmax)
{
    __shared__ float red[4][64];
    const int t = threadIdx.x;
    const int cl = t & 63, rg = t >> 6;
    const int col = blockIdx.x * 64 + cl;
    const int b = blockIdx.y;
    const float* p = qkvm + (size_t)b * 1024 * QK3 + col;
    float mx = 0.f;
    const int n0 = rg * 256;
    for (int n = 0; n < 256; ++n) mx = fmaxf(mx, p[(size_t)(n0 + n) * QK3]);
    red[rg][cl] = mx;
    __syncthreads();
    if (rg == 0) {
        mx = fmaxf(fmaxf(red[0][cl], red[1][cl]), fmaxf(red[2][cl], red[3][cl]));
        cmax[b * QK3 + col] = mx;
    }
}

// ---------------------------------------------------------------------------
// K2b: updated[b,n] (unchanged)
// ---------------------------------------------------------------------------
__global__ __launch_bounds__(TPB)
void k_upd(const float* __restrict__ mask, float* __restrict__ upd)
{
    const int w = threadIdx.x >> 6, lane = threadIdx.x & 63;
    const int r = blockIdx.x * 4 + w;
    if (r >= ROWS) return;
    const int b = r / NTOK, n = r % NTOK;
    float res = 1.f;
    if (n > 0) {
        const float* p = mask + (size_t)(b * (NTOK - 1) + (n - 1)) * DIM;
        float s = 0.f;
        for (int i = lane; i < DIM; i += 64) s += p[i];
#pragma unroll
        for (int off = 32; off > 0; off >>= 1) s += __shfl_xor(s, off, 64);
        res = (s > 0.f) ? 1.f : 0.f;
    }
    if (lane == 0) upd[r] = res;
}

// ---------------------------------------------------------------------------
// K2c: vt ones-row (row 128 per bh): 1.0 for n<NTOK else 0 — the l column
// ---------------------------------------------------------------------------
__global__ __launch_bounds__(TPB)
void k_ones(unsigned short* __restrict__ vt)
{
    const int bh = blockIdx.x;
    unsigned short* p = vt + ((size_t)bh * VROWS + 128) * NPAD;
    for (int n = threadIdx.x; n < NPAD; n += TPB)
        p[n] = (n < NTOK) ? (unsigned short)0x3F80 : (unsigned short)0;
}

// ---------------------------------------------------------------------------
// K3: qe/ke bf16 [bh,1088,64], vt bf16 transposed [bh,129(VROWS),1088]
// ---------------------------------------------------------------------------
__global__ __launch_bounds__(TPB)
void k_prep(const float* __restrict__ qkv, const float* __restrict__ qkvm,
            const float* __restrict__ cmax, unsigned short* __restrict__ qe,
            unsigned short* __restrict__ ke, unsigned short* __restrict__ vt)
{
    __shared__ unsigned short Vt_l[128 * 66];
    const int t = threadIdx.x;
    const int nt = blockIdx.x, h = blockIdx.y, b = blockIdx.z;
    const int bh = b * HEADS + h;
    const int nl = t >> 2, ds0 = (t & 3) * 16;
    const int n = nt * 64 + nl;
    const bool valid = n < NTOK;
    const int col0 = h * DH + ds0;

    unsigned short oq[16] __attribute__((aligned(16)));
    unsigned short ok[16] __attribute__((aligned(16)));

    const size_t row  = (size_t)(b * NTOK + n) * QK3 + col0;
    const size_t mrow = (size_t)(b * 1024 + (n - 1)) * QK3 + col0;
    const int cb = b * QK3 + col0;

#pragma unroll
    for (int i = 0; i < 4; ++i) {
        float qa[4] = {0, 0, 0, 0}, ka[4] = {0, 0, 0, 0}, va[4] = {0, 0, 0, 0};
        float qma[4] = {1, 1, 1, 1}, kma[4] = {1, 1, 1, 1}, vma[4] = {1, 1, 1, 1};
        if (valid) {
            *(float4*)qa = *(const float4*)(qkv + row + i * 4);
            *(float4*)ka = *(const float4*)(qkv + row + 768 + i * 4);
            *(float4*)va = *(const float4*)(qkv + row + 1536 + i * 4);
            if (n > 0) {
                *(float4*)qma = *(const float4*)(qkvm + mrow + i * 4);
                *(float4*)kma = *(const float4*)(qkvm + mrow + 768 + i * 4);
                *(float4*)vma = *(const float4*)(qkvm + mrow + 1536 + i * 4);
#pragma unroll
                for (int j = 0; j < 4; ++j) {
                    qma[j] /= (1e-6f + cmax[cb + i * 4 + j]);
                    kma[j] /= (1e-6f + cmax[cb + 768 + i * 4 + j]);
                    vma[j] /= (1e-6f + cmax[cb + 1536 + i * 4 + j]);
                }
            }
        }
#pragma unroll
        for (int j = 0; j < 4; ++j) {
            const int idx = i * 4 + j, d = ds0 + idx;
            oq[idx] = f2bf(qa[j] * qma[j] * 0.125f);
            ok[idx] = f2bf(ka[j] * kma[j]);
            const float vmv = valid ? vma[j] : 0.f;
            Vt_l[d * 66 + nl]        = f2bf(va[j] * vmv);
            Vt_l[(64 + d) * 66 + nl] = f2bf(vmv);
        }
    }
    if (valid) {
        unsigned short* qp = qe + ((size_t)bh * NPAD + n) * 64 + ds0;
        unsigned short* kp = ke + ((size_t)bh * NPAD + n) * 64 + ds0;
        *(short8*)qp       = *(short8*)oq;
        *(short8*)(qp + 8) = *(short8*)(oq + 8);
        *(short8*)kp       = *(short8*)ok;
        *(short8*)(kp + 8) = *(short8*)(ok + 8);
    }
    __syncthreads();
    const int c = t >> 1, nh = (t & 1) * 32;
    unsigned short ov[32] __attribute__((aligned(16)));
#pragma unroll
    for (int i = 0; i < 32; ++i) ov[i] = Vt_l[c * 66 + nh + i];
    unsigned short* vp = vt + ((size_t)bh * VROWS + c) * NPAD + nt * 64 + nh;
#pragma unroll
    for (int i = 0; i < 4; ++i) *(short8*)(vp + i * 8) = *(short8*)(ov + i * 8);
}

// ---------------------------------------------------------------------------
// K4: MFMA flash attention, fixed-shift softmax (no max/sum reductions).
// R3 structure: LDS-staged K/V shared by 4 waves (via global_load_lds,
// fragment-order LDS). p = exp(S - 10) is exact softmax after the final
// divide by l (acc group 8, V ones-column). No kv masking needed: invalid
// kv rows have V = 0 and ones = 0, so their tiny exp contributions vanish.
// ---------------------------------------------------------------------------
__global__ __launch_bounds__(TPB)
void k_attn(const unsigned short* __restrict__ qe, const unsigned short* __restrict__ ke,
            const unsigned short* __restrict__ vt, const float* __restrict__ upd,
            unsigned short* __restrict__ ab2)
{
    __shared__ short8 KsF[8 * 64];    // g = kk*4 + nc
    __shared__ short8 VsF[18 * 64];   // g = kk*9 + c8 (c8=8 is the ones-group)
    __shared__ short8 PsF[8 * 64];    // 2 groups per wave (wave-private)

    const int t = threadIdx.x;
    const int w = t >> 6, lane = t & 63;
    const int l15 = lane & 15, quad = lane >> 4;
    const int bh = blockIdx.y;
    const int b = bh / HEADS, h = bh % HEADS;
    const int q0 = blockIdx.x * 64;

    short8 qf0, qf1;
    {
        const unsigned short* qp = qe + ((size_t)bh * NPAD + q0 + w * 16 + l15) * 64 + (quad << 3);
        qf0 = *(const short8*)qp;
        qf1 = *(const short8*)(qp + 32);
    }

    f32x4 acc[9];   // 0..7 = 128 out cols, 8 = l column
#pragma unroll
    for (int g = 0; g < 9; ++g) acc[g] = (f32x4){0.f, 0.f, 0.f, 0.f};

    unsigned short* Pw = (unsigned short*)&PsF[w * 2 * 64];

    for (int kt = 0; kt < 17; ++kt) {
        const int kn0 = kt * 64;
        __syncthreads();
        // K stage: wave w -> groups 2w, 2w+1 (global_load_lds, lane-contig dst)
#pragma unroll
        for (int gi = 0; gi < 2; ++gi) {
            const int g = 2 * w + gi, kk = g >> 2, nc = g & 3;
            const unsigned short* gp = ke + ((size_t)bh * NPAD + kn0 + nc * 16 + l15) * 64
                                          + kk * 32 + (quad << 3);
            gl_lds16(gp, (unsigned short*)&KsF[g * 64] + lane * 8);
        }
        // V stage: 18 groups, wave w -> g = w, w+4, ...
        for (int g = w; g < 18; g += 4) {
            const int kk = (g >= 9) ? 1 : 0, c8 = (g >= 9) ? g - 9 : g;
            const unsigned short* gp = vt + ((size_t)bh * VROWS + c8 * 16 + l15) * NPAD
                                          + kn0 + kk * 32 + (quad << 3);
            gl_lds16(gp, (unsigned short*)&VsF[g * 64] + lane * 8);
        }
        __syncthreads();

        // S = Q K^T
        f32x4 s[4];
#pragma unroll
        for (int nc = 0; nc < 4; ++nc) {
            f32x4 z = (f32x4){0.f, 0.f, 0.f, 0.f};
            z = __builtin_amdgcn_mfma_f32_16x16x32_bf16(qf0, KsF[nc * 64 + lane], z, 0, 0, 0);
            z = __builtin_amdgcn_mfma_f32_16x16x32_bf16(qf1, KsF[(4 + nc) * 64 + lane], z, 0, 0, 0);
            s[nc] = z;
        }
        // p = exp(S - 10): exact softmax after the final 1/l (constant shift)
#pragma unroll
        for (int nc = 0; nc < 4; ++nc)
#pragma unroll
            for (int r = 0; r < 4; ++r)
                s[nc][r] = __expf(s[nc][r] - 10.f);
        // P: C-layout regs -> A-layout LDS (wave-private slice)
#pragma unroll
        for (int nc = 0; nc < 4; ++nc) {
            const int k = nc * 16 + l15;
            const int kk = nc >> 1;
            const int sb = ((k >> 3) & 3) << 4;
            const int j = k & 7;
#pragma unroll
            for (int r = 0; r < 4; ++r)
                Pw[kk * 512 + (quad * 4 + r + sb) * 8 + j] = f2bf(s[nc][r]);
        }
        const short8 pf0 = PsF[(w * 2 + 0) * 64 + lane];
        const short8 pf1 = PsF[(w * 2 + 1) * 64 + lane];
        // O += P V  (9 independent acc chains, incl. l column)
#pragma unroll
        for (int g = 0; g < 9; ++g) {
            acc[g] = __builtin_amdgcn_mfma_f32_16x16x32_bf16(pf0, VsF[g * 64 + lane], acc[g], 0, 0, 0);
            acc[g] = __builtin_amdgcn_mfma_f32_16x16x32_bf16(pf1, VsF[(9 + g) * 64 + lane], acc[g], 0, 0, 0);
        }
    }

    // l lives in the l15==0 column of acc[8]; broadcast within each quad
    float lb[4];
#pragma unroll
    for (int r = 0; r < 4; ++r) lb[r] = __shfl(acc[8][r], lane & 48, 64);

#pragma unroll
    for (int r = 0; r < 4; ++r) {
        const int row = q0 + w * 16 + quad * 4 + r;
        if (row < NTOK) {
            const size_t rg = (size_t)b * NTOK + row;
            const float inv = upd[rg] / lb[r];
#pragma unroll
            for (int g = 0; g < 8; ++g) {
                const int c = g * 16 + l15;
                const size_t addr = (size_t)(c >> 6) * APLANE + rg * DIM + h * 64 + (c & 63);
                ab2[addr] = f2bf(acc[g][r] * inv);
            }
        }
    }
}

// ---------------------------------------------------------------------------
// K5: bf16 MFMA out-GEMMs (unchanged)
// ---------------------------------------------------------------------------
__global__ __launch_bounds__(TPB)
void k_gemm_out_mfma(const unsigned short* __restrict__ ab2,
                     const unsigned short* __restrict__ Wo,
                     const float* __restrict__ bout, float* __restrict__ dout)
{
    const int z = blockIdx.z;
    const unsigned short* A = ab2 + (size_t)z * APLANE;
    const unsigned short* B = Wo + (size_t)z * DIM * DIM;

    __shared__ unsigned short As[128 * 32];
    __shared__ unsigned short Bs[128 * 32];

    const int t = threadIdx.x;
    const int w = t >> 6, lane = t & 63, l15 = lane & 15, quad = lane >> 4;
    const int rowT = blockIdx.y * 128, colT = blockIdx.x * 128;
    const int wm = (w & 1) * 64, wn = (w >> 1) * 64;

    const int r0 = t >> 2, kc = (t & 3) * 8;
    const unsigned short* Ap = A + (size_t)(rowT + r0) * DIM + kc;
    const unsigned short* Bp = B + (size_t)(colT + r0) * DIM + kc;

    f32x4 acc[4][4];
#pragma unroll
    for (int i = 0; i < 4; ++i)
#pragma unroll
        for (int j = 0; j < 4; ++j) acc[i][j] = (f32x4){0.f, 0.f, 0.f, 0.f};

    for (int k0 = 0; k0 < DIM; k0 += 32) {
        __syncthreads();
        gl_lds16(Ap + k0,            As + t * 8);
        gl_lds16(Ap + 64 * DIM + k0, As + (t + 256) * 8);
        gl_lds16(Bp + k0,            Bs + t * 8);
        gl_lds16(Bp + 64 * DIM + k0, Bs + (t + 256) * 8);
        __syncthreads();
        short8 fa[4], fb[4];
#pragma unroll
        for (int mi = 0; mi < 4; ++mi)
            fa[mi] = *(const short8*)(As + (wm + mi * 16 + l15) * 32 + quad * 8);
#pragma unroll
        for (int ni = 0; ni < 4; ++ni)
            fb[ni] = *(const short8*)(Bs + (wn + ni * 16 + l15) * 32 + quad * 8);
#pragma unroll
        for (int mi = 0; mi < 4; ++mi)
#pragma unroll
            for (int ni = 0; ni < 4; ++ni)
                acc[mi][ni] = __builtin_amdgcn_mfma_f32_16x16x32_bf16(fa[mi], fb[ni], acc[mi][ni], 0, 0, 0);
    }
#pragma unroll
    for (int mi = 0; mi < 4; ++mi)
#pragma unroll
        for (int ni = 0; ni < 4; ++ni) {
            const int col = colT + wn + ni * 16 + l15;
            const float bb = (z == 0) ? bout[col] : 0.f;
#pragma unroll
            for (int r = 0; r < 4; ++r) {
                const int row = rowT + wm + mi * 16 + quad * 4 + r;
                if (row >= ROWS) continue;
                const int b = row / NTOK, n = row % NTOK;
                if (z == 0) {
                    dout[(size_t)row * DIM + col] = acc[mi][ni][r] + bb;
                } else if (n >= 1) {
                    dout[OUT0 + ((size_t)(b * (NTOK - 1) + (n - 1))) * DIM + col] = acc[mi][ni][r];
                }
            }
        }
}

extern "C" void kernel_launch(void* const* d_in, const int* in_sizes, int n_in,
                              void* d_out, int out_size, void* d_ws, size_t ws_size,
                              hipStream_t stream)
{
    const float* x    = (const float*)d_in[0];
    const float* mask = (const float*)d_in[1];
    const float* wqkv = (const float*)d_in[2];
    const float* wout = (const float*)d_in[3];
    const float* bout = (const float*)d_in[4];
    float* ws   = (float*)d_ws;
    float* qkv  = ws + OFF_QKV;
    float* qkvm = ws + OFF_QKVM;
    unsigned short* qe  = (unsigned short*)(ws + OFF_QE);
    unsigned short* ke  = (unsigned short*)(ws + OFF_KE);
    unsigned short* vt  = (unsigned short*)(ws + OFF_VT);
    unsigned short* abf = (unsigned short*)(ws + OFF_ABF);
    unsigned short* wq  = (unsigned short*)(ws + OFF_WQ);
    unsigned short* wo  = (unsigned short*)(ws + OFF_WO);
    float* cmax = ws + OFF_CMAX;
    float* upd  = ws + OFF_UPD;
    float* out  = (float*)d_out;

    hipLaunchKernelGGL(k_cvt,           dim3(1584, 1, 4), dim3(TPB), 0, stream, x, mask, wqkv, wout, abf, wq, wo);
    hipLaunchKernelGGL(k_gemm_qkv_mfma, dim3(18, 33, 2),  dim3(TPB), 0, stream, abf, wq, qkv, qkvm);
    hipLaunchKernelGGL(k_colmax,        dim3(36, 4),      dim3(TPB), 0, stream, qkvm, cmax);
    hipLaunchKernelGGL(k_upd,           dim3(1025),       dim3(TPB), 0, stream, mask, upd);
    hipLaunchKernelGGL(k_ones,          dim3(48),         dim3(TPB), 0, stream, vt);
    hipLaunchKernelGGL(k_prep,          dim3(17, 12, 4),  dim3(TPB), 0, stream, qkv, qkvm, cmax, qe, ke, vt);
    hipLaunchKernelGGL(k_attn,          dim3(17, 48),     dim3(TPB), 0, stream, qe, ke, vt, upd, abf);
    hipLaunchKernelGGL(k_gemm_out_mfma, dim3(6, 33, 2),   dim3(TPB), 0, stream, abf, wo, bout, out);
}

// Round 6
// 255.685 us; speedup vs baseline: 1.9174x; 1.3657x over previous
//
#include <hip/hip_runtime.h>
#include <cmath>

#define TPB 256

static const int NTOK  = 1025;
static const int DIM   = 768;
static const int HEADS = 12;
static const int QK3   = 2304;
static const int ROWS  = 4 * NTOK;        // 4100
static const int MROWS = 4 * (NTOK - 1);  // 4096
static const int MPAD  = 4224;            // 33*128 padded A rows
static const int NPAD  = 1088;            // 17*64
static const int VROWS = 129;             // 128 V cols + 1 ones-row (l column)
static const size_t OUT0 = (size_t)ROWS * DIM;
static const size_t APLANE = (size_t)MPAD * DIM;   // bf16 per plane

// workspace offsets in floats (qkv/qkvm now bf16)
static const size_t OFF_QKV16  = 0;          // 4100*2304 u16 = 4,723,200 f
static const size_t OFF_QKVM16 = 4800000;    // 4096*2304 u16 = 4,718,592 f
static const size_t OFF_QE     = 9600000;    // 48*1088*64 u16 = 1,671,168 f
static const size_t OFF_KE     = 11300000;   // 1,671,168 f
static const size_t OFF_VT     = 13000000;   // 48*129*1088 u16 = 3,368,448 f
static const size_t OFF_ABF    = 16400000;   // 2*4224*768 u16 = 3,244,032 f
static const size_t OFF_WQ     = 19700000;   // 2*2304*768 u16 = 1,769,472 f
static const size_t OFF_WO     = 21500000;   // 2*768*768 u16  =   589,824 f
static const size_t OFF_CMAX   = 22100000;   // 9,216 f
static const size_t OFF_UPD    = 22110000;   // 4,100 f
// k_attn ones-group staging reads vt rows 129..143 of the last bh: lands in
// the VT->ABF gap (mapped, finite poison); those acc rows are never used.

typedef __attribute__((ext_vector_type(8))) short short8;
typedef __attribute__((ext_vector_type(4))) float f32x4;

__device__ __forceinline__ unsigned short f2bf(float f) {
    union { float f; unsigned int u; } c; c.f = f;
    unsigned int u = c.u + 0x7fffu + ((c.u >> 16) & 1u);  // RNE
    return (unsigned short)(u >> 16);
}
__device__ __forceinline__ float bf2f(unsigned short u) {
    union { unsigned int u; float f; } c; c.u = (unsigned int)u << 16;
    return c.f;
}
__device__ __forceinline__ void gl_lds16(const unsigned short* g, unsigned short* l) {
    __builtin_amdgcn_global_load_lds(
        (const __attribute__((address_space(1))) unsigned int*)g,
        (__attribute__((address_space(3))) unsigned int*)l, 16, 0, 0);
}

// ---------------------------------------------------------------------------
// K0: fp32 -> bf16 conversions (unchanged)
// ---------------------------------------------------------------------------
__global__ __launch_bounds__(TPB)
void k_cvt(const float* __restrict__ x, const float* __restrict__ mask,
           const float* __restrict__ wqkv, const float* __restrict__ wout,
           unsigned short* __restrict__ Abf, unsigned short* __restrict__ Wq,
           unsigned short* __restrict__ Wo)
{
    const int z = blockIdx.z;
    const size_t idx = ((size_t)blockIdx.x * TPB + threadIdx.x) * 8;
    unsigned short o[8] __attribute__((aligned(16)));
    if (z <= 1) {
        if (idx >= APLANE) return;
        const int row = (int)(idx / DIM);
        const int M = z ? MROWS : ROWS;
        const float* src = z ? mask : x;
        if (row < M) {
            float a[8];
            *(float4*)&a[0] = *(const float4*)(src + idx);
            *(float4*)&a[4] = *(const float4*)(src + idx + 4);
#pragma unroll
            for (int i = 0; i < 8; ++i) o[i] = f2bf(a[i]);
        } else {
#pragma unroll
            for (int i = 0; i < 8; ++i) o[i] = 0;
        }
        *(short8*)(Abf + (size_t)z * APLANE + idx) = *(short8*)o;
    } else {
        const size_t tot = (z == 2) ? (size_t)QK3 * DIM : (size_t)DIM * DIM;
        if (idx >= tot) return;
        const float* src = (z == 2) ? wqkv : wout;
        unsigned short* dst = (z == 2) ? Wq : Wo;
        float a[8];
        *(float4*)&a[0] = *(const float4*)(src + idx);
        *(float4*)&a[4] = *(const float4*)(src + idx + 4);
        unsigned short oa[8] __attribute__((aligned(16)));
#pragma unroll
        for (int i = 0; i < 8; ++i) { o[i] = f2bf(a[i]); oa[i] = f2bf(fabsf(a[i])); }
        *(short8*)(dst + idx) = *(short8*)o;
        *(short8*)(dst + tot + idx) = *(short8*)oa;
    }
}

// ---------------------------------------------------------------------------
// K1: bf16 MFMA GEMM, BK=64 (slab LDS layout), bf16 C output.
// z=0: qkv16 = x @ w^T ; z=1: qkvm16 = mask @ |w|^T, + fused col-max
// (atomicMax on non-negative float bit patterns) into cmax[b][col].
// ---------------------------------------------------------------------------
__global__ __launch_bounds__(TPB)
void k_gemm_qkv_mfma(const unsigned short* __restrict__ Abf,
                     const unsigned short* __restrict__ Wq,
                     unsigned short* __restrict__ qkv16,
                     unsigned short* __restrict__ qkvm16,
                     float* __restrict__ cmax)
{
    const int z = blockIdx.z;
    const int rowT = blockIdx.y * 128, colT = blockIdx.x * 128;
    if (z == 1 && rowT >= MROWS) return;
    const unsigned short* A = Abf + (size_t)z * APLANE;
    const unsigned short* B = Wq + (size_t)z * QK3 * DIM;

    __shared__ unsigned short As[128 * 64];   // two 128x32 slabs
    __shared__ unsigned short Bs[128 * 64];

    const int t = threadIdx.x;
    const int w = t >> 6, lane = t & 63, l15 = lane & 15, quad = lane >> 4;
    const int wm = (w & 1) * 64, wn = (w >> 1) * 64;
    const int sr = t >> 2, sk = (t & 3) * 8;

    f32x4 acc[4][4];
#pragma unroll
    for (int i = 0; i < 4; ++i)
#pragma unroll
        for (int j = 0; j < 4; ++j) acc[i][j] = (f32x4){0.f, 0.f, 0.f, 0.f};

    for (int k0 = 0; k0 < DIM; k0 += 64) {
        __syncthreads();
#pragma unroll
        for (int c = 0; c < 4; ++c) {
            const int gr = sr + (c & 1) * 64;
            const int gk = k0 + (c >> 1) * 32 + sk;
            gl_lds16(A + (size_t)(rowT + gr) * DIM + gk, As + c * 2048 + t * 8);
            gl_lds16(B + (size_t)(colT + gr) * DIM + gk, Bs + c * 2048 + t * 8);
        }
        __syncthreads();
        short8 fa[2][4], fb[2][4];
#pragma unroll
        for (int kk = 0; kk < 2; ++kk) {
#pragma unroll
            for (int mi = 0; mi < 4; ++mi)
                fa[kk][mi] = *(const short8*)(As + kk * 4096 + (wm + mi * 16 + l15) * 32 + quad * 8);
#pragma unroll
            for (int ni = 0; ni < 4; ++ni)
                fb[kk][ni] = *(const short8*)(Bs + kk * 4096 + (wn + ni * 16 + l15) * 32 + quad * 8);
        }
#pragma unroll
        for (int kk = 0; kk < 2; ++kk)
#pragma unroll
            for (int mi = 0; mi < 4; ++mi)
#pragma unroll
                for (int ni = 0; ni < 4; ++ni)
                    acc[mi][ni] = __builtin_amdgcn_mfma_f32_16x16x32_bf16(fa[kk][mi], fb[kk][ni], acc[mi][ni], 0, 0, 0);
    }

    float cm[4] = {0.f, 0.f, 0.f, 0.f};
#pragma unroll
    for (int mi = 0; mi < 4; ++mi)
#pragma unroll
        for (int ni = 0; ni < 4; ++ni) {
            const int col = colT + wn + ni * 16 + l15;
#pragma unroll
            for (int r = 0; r < 4; ++r) {
                const int row = rowT + wm + mi * 16 + quad * 4 + r;
                const float v = acc[mi][ni][r];
                if (z == 0) {
                    if (row < ROWS) qkv16[(size_t)row * QK3 + col] = f2bf(v);
                } else {
                    qkvm16[(size_t)row * QK3 + col] = f2bf(v);
                    cm[ni] = fmaxf(cm[ni], v);
                }
            }
        }
    if (z == 1) {
        const int bb = rowT >> 10;
#pragma unroll
        for (int ni = 0; ni < 4; ++ni) {
            float m = cm[ni];
            m = fmaxf(m, __shfl_xor(m, 16, 64));
            m = fmaxf(m, __shfl_xor(m, 32, 64));
            if (quad == 0)
                atomicMax((int*)&cmax[bb * QK3 + colT + wn + ni * 16 + l15], __float_as_int(m));
        }
    }
}

// ---------------------------------------------------------------------------
// K2: merged small kernels: bx<1025 -> updated[]; bx>=1025 -> vt ones-row
// ---------------------------------------------------------------------------
__global__ __launch_bounds__(TPB)
void k_misc(const float* __restrict__ mask, float* __restrict__ upd,
            unsigned short* __restrict__ vt)
{
    const int bx = blockIdx.x;
    if (bx >= 1025) {
        const int bh = bx - 1025;
        unsigned short* p = vt + ((size_t)bh * VROWS + 128) * NPAD;
        for (int n = threadIdx.x; n < NPAD; n += TPB)
            p[n] = (n < NTOK) ? (unsigned short)0x3F80 : (unsigned short)0;
        return;
    }
    const int w = threadIdx.x >> 6, lane = threadIdx.x & 63;
    const int r = bx * 4 + w;
    if (r >= ROWS) return;
    const int b = r / NTOK, n = r % NTOK;
    float res = 1.f;
    if (n > 0) {
        const float* p = mask + (size_t)(b * (NTOK - 1) + (n - 1)) * DIM;
        float s = 0.f;
        for (int i = lane; i < DIM; i += 64) s += p[i];
#pragma unroll
        for (int off = 32; off > 0; off >>= 1) s += __shfl_xor(s, off, 64);
        res = (s > 0.f) ? 1.f : 0.f;
    }
    if (lane == 0) upd[r] = res;
}

// ---------------------------------------------------------------------------
// K3: qe/ke bf16 [bh,1088,64], vt bf16 transposed [bh,129,1088] (bf16 inputs)
// ---------------------------------------------------------------------------
__global__ __launch_bounds__(TPB)
void k_prep(const unsigned short* __restrict__ qkv16,
            const unsigned short* __restrict__ qkvm16,
            const float* __restrict__ cmax, unsigned short* __restrict__ qe,
            unsigned short* __restrict__ ke, unsigned short* __restrict__ vt)
{
    __shared__ unsigned short Vt_l[128 * 66];
    const int t = threadIdx.x;
    const int nt = blockIdx.x, h = blockIdx.y, b = blockIdx.z;
    const int bh = b * HEADS + h;
    const int nl = t >> 2, ds0 = (t & 3) * 16;
    const int n = nt * 64 + nl;
    const bool valid = n < NTOK;
    const int col0 = h * 64 + ds0;

    unsigned short q16[16] __attribute__((aligned(16))) = {0};
    unsigned short k16[16] __attribute__((aligned(16))) = {0};
    unsigned short v16[16] __attribute__((aligned(16))) = {0};
    unsigned short qm16[16] __attribute__((aligned(16)));
    unsigned short km16[16] __attribute__((aligned(16)));
    unsigned short vm16[16] __attribute__((aligned(16)));
    float cq[16], ck[16], cv[16];

    const bool useM = valid && (n > 0);
    if (valid) {
        const size_t br = (size_t)(b * NTOK + n) * QK3 + col0;
        *(short8*)&q16[0] = *(const short8*)(qkv16 + br);
        *(short8*)&q16[8] = *(const short8*)(qkv16 + br + 8);
        *(short8*)&k16[0] = *(const short8*)(qkv16 + br + 768);
        *(short8*)&k16[8] = *(const short8*)(qkv16 + br + 776);
        *(short8*)&v16[0] = *(const short8*)(qkv16 + br + 1536);
        *(short8*)&v16[8] = *(const short8*)(qkv16 + br + 1544);
    }
    if (useM) {
        const size_t mr = (size_t)(b * 1024 + (n - 1)) * QK3 + col0;
        *(short8*)&qm16[0] = *(const short8*)(qkvm16 + mr);
        *(short8*)&qm16[8] = *(const short8*)(qkvm16 + mr + 8);
        *(short8*)&km16[0] = *(const short8*)(qkvm16 + mr + 768);
        *(short8*)&km16[8] = *(const short8*)(qkvm16 + mr + 776);
        *(short8*)&vm16[0] = *(const short8*)(qkvm16 + mr + 1536);
        *(short8*)&vm16[8] = *(const short8*)(qkvm16 + mr + 1544);
        const int cb = b * QK3 + col0;
#pragma unroll
        for (int i = 0; i < 4; ++i) {
            *(float4*)&cq[i * 4] = *(const float4*)(cmax + cb + i * 4);
            *(float4*)&ck[i * 4] = *(const float4*)(cmax + cb + 768 + i * 4);
            *(float4*)&cv[i * 4] = *(const float4*)(cmax + cb + 1536 + i * 4);
        }
    }

    unsigned short oq[16] __attribute__((aligned(16)));
    unsigned short ok[16] __attribute__((aligned(16)));
#pragma unroll
    for (int idx = 0; idx < 16; ++idx) {
        const float qm = useM ? bf2f(qm16[idx]) / (1e-6f + cq[idx]) : 1.f;
        const float km = useM ? bf2f(km16[idx]) / (1e-6f + ck[idx]) : 1.f;
        const float vm = valid ? (useM ? bf2f(vm16[idx]) / (1e-6f + cv[idx]) : 1.f) : 0.f;
        oq[idx] = f2bf(bf2f(q16[idx]) * qm * 0.125f);
        ok[idx] = f2bf(bf2f(k16[idx]) * km);
        const int d = ds0 + idx;
        Vt_l[d * 66 + nl]        = f2bf(bf2f(v16[idx]) * vm);
        Vt_l[(64 + d) * 66 + nl] = f2bf(vm);
    }
    if (valid) {
        unsigned short* qp = qe + ((size_t)bh * NPAD + n) * 64 + ds0;
        unsigned short* kp = ke + ((size_t)bh * NPAD + n) * 64 + ds0;
        *(short8*)qp       = *(short8*)oq;
        *(short8*)(qp + 8) = *(short8*)(oq + 8);
        *(short8*)kp       = *(short8*)ok;
        *(short8*)(kp + 8) = *(short8*)(ok + 8);
    }
    __syncthreads();
    const int c = t >> 1, nh = (t & 1) * 32;
    unsigned short ov[32] __attribute__((aligned(16)));
#pragma unroll
    for (int i = 0; i < 32; ++i) ov[i] = Vt_l[c * 66 + nh + i];
    unsigned short* vp = vt + ((size_t)bh * VROWS + c) * NPAD + nt * 64 + nh;
#pragma unroll
    for (int i = 0; i < 4; ++i) *(short8*)(vp + i * 8) = *(short8*)(ov + i * 8);
}

// ---------------------------------------------------------------------------
// K4: MFMA flash attention, operand-swapped (no P LDS round-trip).
//   S^T = mfma(K-frag, Q-frag): C row=kv(quad*4+r), col=q(l15)
//   P^T B-frags built by register permute (shfl) from S^T C-regs
//   O^T = mfma(V^T-frag, P^T-frag): row=d, col=q; l via ones-row (acc[8] r0 q0)
// Fixed-shift softmax exp(S-10); invalid kv rows have V=ones=0.
// ---------------------------------------------------------------------------
__global__ __launch_bounds__(TPB)
void k_attn(const unsigned short* __restrict__ qe, const unsigned short* __restrict__ ke,
            const unsigned short* __restrict__ vt, const float* __restrict__ upd,
            unsigned short* __restrict__ ab2)
{
    __shared__ short8 KsF[8 * 64];    // g = kk*4 + nc
    __shared__ short8 VsF[18 * 64];   // g = kk*9 + c8 (c8=8 is the ones-group)

    const int t = threadIdx.x;
    const int w = t >> 6, lane = t & 63;
    const int l15 = lane & 15, quad = lane >> 4;
    const int bh = blockIdx.y;
    const int b = bh / HEADS, h = bh % HEADS;
    const int q0 = blockIdx.x * 64;
    const int qrow = q0 + w * 16 + l15;     // this lane's q (as S^T col)

    short8 qf0, qf1;
    {
        const unsigned short* qp = qe + ((size_t)bh * NPAD + qrow) * 64 + (quad << 3);
        qf0 = *(const short8*)qp;
        qf1 = *(const short8*)(qp + 32);
    }
    const int pA = (quad & 1) * 32 + l15;   // shuffle source lanes
    const int pB = pA + 16;
    const bool lo32 = (lane < 32);

    f32x4 acc[9];   // 0..7 = 128 out cols (d), 8 = l column
#pragma unroll
    for (int g = 0; g < 9; ++g) acc[g] = (f32x4){0.f, 0.f, 0.f, 0.f};

    for (int kt = 0; kt < 17; ++kt) {
        const int kn0 = kt * 64;
        __syncthreads();
#pragma unroll
        for (int gi = 0; gi < 2; ++gi) {
            const int g = 2 * w + gi, kk = g >> 2, nc = g & 3;
            const unsigned short* gp = ke + ((size_t)bh * NPAD + kn0 + nc * 16 + l15) * 64
                                          + kk * 32 + (quad << 3);
            gl_lds16(gp, (unsigned short*)&KsF[g * 64] + lane * 8);
        }
        for (int g = w; g < 18; g += 4) {
            const int kk = (g >= 9) ? 1 : 0, c8 = g - kk * 9;
            const unsigned short* gp = vt + ((size_t)bh * VROWS + c8 * 16 + l15) * NPAD
                                          + kn0 + kk * 32 + (quad << 3);
            gl_lds16(gp, (unsigned short*)&VsF[g * 64] + lane * 8);
        }
        __syncthreads();

        // S^T: rows kv (quad*4+r within block nc), cols q (l15)
        f32x4 s[4];
#pragma unroll
        for (int nc = 0; nc < 4; ++nc) {
            f32x4 z = (f32x4){0.f, 0.f, 0.f, 0.f};
            z = __builtin_amdgcn_mfma_f32_16x16x32_bf16(KsF[nc * 64 + lane], qf0, z, 0, 0, 0);
            z = __builtin_amdgcn_mfma_f32_16x16x32_bf16(KsF[(4 + nc) * 64 + lane], qf1, z, 0, 0, 0);
            s[nc] = z;
        }
        // p = exp(S - 10): exact softmax after final 1/l
        unsigned int dA[4], dB[4];
#pragma unroll
        for (int nc = 0; nc < 4; ++nc) {
            const float p0 = __expf(s[nc][0] - 10.f);
            const float p1 = __expf(s[nc][1] - 10.f);
            const float p2 = __expf(s[nc][2] - 10.f);
            const float p3 = __expf(s[nc][3] - 10.f);
            dA[nc] = (unsigned int)f2bf(p0) | ((unsigned int)f2bf(p1) << 16);
            dB[nc] = (unsigned int)f2bf(p2) | ((unsigned int)f2bf(p3) << 16);
        }
        // P^T B-frags via register permute
        union { int i[4]; short8 s; } u0, u1;
        {
            const int a0 = __shfl((int)dA[0], pA, 64), a1 = __shfl((int)dA[1], pA, 64);
            const int b0 = __shfl((int)dB[0], pA, 64), b1 = __shfl((int)dB[1], pA, 64);
            const int a2 = __shfl((int)dA[0], pB, 64), a3 = __shfl((int)dA[1], pB, 64);
            const int b2 = __shfl((int)dB[0], pB, 64), b3 = __shfl((int)dB[1], pB, 64);
            u0.i[0] = lo32 ? a0 : a1;
            u0.i[1] = lo32 ? b0 : b1;
            u0.i[2] = lo32 ? a2 : a3;
            u0.i[3] = lo32 ? b2 : b3;
        }
        {
            const int a0 = __shfl((int)dA[2], pA, 64), a1 = __shfl((int)dA[3], pA, 64);
            const int b0 = __shfl((int)dB[2], pA, 64), b1 = __shfl((int)dB[3], pA, 64);
            const int a2 = __shfl((int)dA[2], pB, 64), a3 = __shfl((int)dA[3], pB, 64);
            const int b2 = __shfl((int)dB[2], pB, 64), b3 = __shfl((int)dB[3], pB, 64);
            u1.i[0] = lo32 ? a0 : a1;
            u1.i[1] = lo32 ? b0 : b1;
            u1.i[2] = lo32 ? a2 : a3;
            u1.i[3] = lo32 ? b2 : b3;
        }
        const short8 pf0 = u0.s, pf1 = u1.s;
        // O^T += V^T P^T  (9 independent chains incl. l column)
#pragma unroll
        for (int g = 0; g < 9; ++g) {
            acc[g] = __builtin_amdgcn_mfma_f32_16x16x32_bf16(VsF[g * 64 + lane], pf0, acc[g], 0, 0, 0);
            acc[g] = __builtin_amdgcn_mfma_f32_16x16x32_bf16(VsF[(9 + g) * 64 + lane], pf1, acc[g], 0, 0, 0);
        }
    }

    // l(q) sits at quad==0, reg 0 of acc[8], lane l15 = q
    const float lq = __shfl(acc[8][0], l15, 64);
    if (qrow < NTOK) {
        const size_t rg = (size_t)b * NTOK + qrow;
        const float inv = upd[rg] / lq;
#pragma unroll
        for (int g = 0; g < 8; ++g) {
            uint2 pk;
            pk.x = (unsigned int)f2bf(acc[g][0] * inv) | ((unsigned int)f2bf(acc[g][1] * inv) << 16);
            pk.y = (unsigned int)f2bf(acc[g][2] * inv) | ((unsigned int)f2bf(acc[g][3] * inv) << 16);
            const size_t addr = (size_t)(g >> 2) * APLANE + rg * DIM + h * 64 + (g & 3) * 16 + quad * 4;
            *(uint2*)(ab2 + addr) = pk;
        }
    }
}

// ---------------------------------------------------------------------------
// K5: bf16 MFMA out-GEMMs (unchanged)
// ---------------------------------------------------------------------------
__global__ __launch_bounds__(TPB)
void k_gemm_out_mfma(const unsigned short* __restrict__ ab2,
                     const unsigned short* __restrict__ Wo,
                     const float* __restrict__ bout, float* __restrict__ dout)
{
    const int z = blockIdx.z;
    const unsigned short* A = ab2 + (size_t)z * APLANE;
    const unsigned short* B = Wo + (size_t)z * DIM * DIM;

    __shared__ unsigned short As[128 * 32];
    __shared__ unsigned short Bs[128 * 32];

    const int t = threadIdx.x;
    const int w = t >> 6, lane = t & 63, l15 = lane & 15, quad = lane >> 4;
    const int rowT = blockIdx.y * 128, colT = blockIdx.x * 128;
    const int wm = (w & 1) * 64, wn = (w >> 1) * 64;

    const int r0 = t >> 2, kc = (t & 3) * 8;
    const unsigned short* Ap = A + (size_t)(rowT + r0) * DIM + kc;
    const unsigned short* Bp = B + (size_t)(colT + r0) * DIM + kc;

    f32x4 acc[4][4];
#pragma unroll
    for (int i = 0; i < 4; ++i)
#pragma unroll
        for (int j = 0; j < 4; ++j) acc[i][j] = (f32x4){0.f, 0.f, 0.f, 0.f};

    for (int k0 = 0; k0 < DIM; k0 += 32) {
        __syncthreads();
        gl_lds16(Ap + k0,            As + t * 8);
        gl_lds16(Ap + 64 * DIM + k0, As + (t + 256) * 8);
        gl_lds16(Bp + k0,            Bs + t * 8);
        gl_lds16(Bp + 64 * DIM + k0, Bs + (t + 256) * 8);
        __syncthreads();
        short8 fa[4], fb[4];
#pragma unroll
        for (int mi = 0; mi < 4; ++mi)
            fa[mi] = *(const short8*)(As + (wm + mi * 16 + l15) * 32 + quad * 8);
#pragma unroll
        for (int ni = 0; ni < 4; ++ni)
            fb[ni] = *(const short8*)(Bs + (wn + ni * 16 + l15) * 32 + quad * 8);
#pragma unroll
        for (int mi = 0; mi < 4; ++mi)
#pragma unroll
            for (int ni = 0; ni < 4; ++ni)
                acc[mi][ni] = __builtin_amdgcn_mfma_f32_16x16x32_bf16(fa[mi], fb[ni], acc[mi][ni], 0, 0, 0);
    }
#pragma unroll
    for (int mi = 0; mi < 4; ++mi)
#pragma unroll
        for (int ni = 0; ni < 4; ++ni) {
            const int col = colT + wn + ni * 16 + l15;
            const float bb = (z == 0) ? bout[col] : 0.f;
#pragma unroll
            for (int r = 0; r < 4; ++r) {
                const int row = rowT + wm + mi * 16 + quad * 4 + r;
                if (row >= ROWS) continue;
                const int b = row / NTOK, n = row % NTOK;
                if (z == 0) {
                    dout[(size_t)row * DIM + col] = acc[mi][ni][r] + bb;
                } else if (n >= 1) {
                    dout[OUT0 + ((size_t)(b * (NTOK - 1) + (n - 1))) * DIM + col] = acc[mi][ni][r];
                }
            }
        }
}

extern "C" void kernel_launch(void* const* d_in, const int* in_sizes, int n_in,
                              void* d_out, int out_size, void* d_ws, size_t ws_size,
                              hipStream_t stream)
{
    const float* x    = (const float*)d_in[0];
    const float* mask = (const float*)d_in[1];
    const float* wqkv = (const float*)d_in[2];
    const float* wout = (const float*)d_in[3];
    const float* bout = (const float*)d_in[4];
    float* ws = (float*)d_ws;
    unsigned short* qkv16  = (unsigned short*)(ws + OFF_QKV16);
    unsigned short* qkvm16 = (unsigned short*)(ws + OFF_QKVM16);
    unsigned short* qe  = (unsigned short*)(ws + OFF_QE);
    unsigned short* ke  = (unsigned short*)(ws + OFF_KE);
    unsigned short* vt  = (unsigned short*)(ws + OFF_VT);
    unsigned short* abf = (unsigned short*)(ws + OFF_ABF);
    unsigned short* wq  = (unsigned short*)(ws + OFF_WQ);
    unsigned short* wo  = (unsigned short*)(ws + OFF_WO);
    float* cmax = ws + OFF_CMAX;
    float* upd  = ws + OFF_UPD;
    float* out  = (float*)d_out;

    hipMemsetAsync(cmax, 0, 9216 * sizeof(float), stream);
    hipLaunchKernelGGL(k_cvt,           dim3(1584, 1, 4), dim3(TPB), 0, stream, x, mask, wqkv, wout, abf, wq, wo);
    hipLaunchKernelGGL(k_gemm_qkv_mfma, dim3(18, 33, 2),  dim3(TPB), 0, stream, abf, wq, qkv16, qkvm16, cmax);
    hipLaunchKernelGGL(k_misc,          dim3(1073),       dim3(TPB), 0, stream, mask, upd, vt);
    hipLaunchKernelGGL(k_prep,          dim3(17, 12, 4),  dim3(TPB), 0, stream, qkv16, qkvm16, cmax, qe, ke, vt);
    hipLaunchKernelGGL(k_attn,          dim3(17, 48),     dim3(TPB), 0, stream, qe, ke, vt, upd, abf);
    hipLaunchKernelGGL(k_gemm_out_mfma, dim3(6, 33, 2),   dim3(TPB), 0, stream, abf, wo, bout, out);
}